// Round 8
// baseline (879.281 us; speedup 1.0000x reference)
//
#include <hip/hip_runtime.h>
#include <hip/hip_bf16.h>
#include <stdint.h>
#include <stddef.h>

#define TM 16      // output rows per tile (MFMA M)
#define CIN 64     // C_in
#define NK3 27     // K3 neighbors
#define COUT 128   // C_out
#define EPS_LN 1e-3f
#define NCH (NK3 * CIN / 32)     // 54 k-chunks of 32
#define NT  (COUT / 16)          // 8 column tiles
#define PK_BYTES (NT * NCH * 64 * 8 * 2)   // 442368

typedef __attribute__((ext_vector_type(8))) short   short8;   // MFMA A/B frag (8 bf16)
typedef __attribute__((ext_vector_type(4))) float   floatx4;  // MFMA C/D frag

__device__ __forceinline__ unsigned short f2b(float f) {
    union { float f; unsigned int i; } v;
    v.f = f;
    unsigned int i = v.i; // RNE bf16
    return (unsigned short)((i + 0x7fffu + ((i >> 16) & 1u)) >> 16);
}

// 8 fp32 -> 8 bf16 (RNE, packed cvt)
__device__ __forceinline__ short8 cvt8(const float* a) {
    union { __hip_bfloat162 h[4]; short8 s; } u;
    u.h[0] = __float22bfloat162_rn(make_float2(a[0], a[1]));
    u.h[1] = __float22bfloat162_rn(make_float2(a[2], a[3]));
    u.h[2] = __float22bfloat162_rn(make_float2(a[4], a[5]));
    u.h[3] = __float22bfloat162_rn(make_float2(a[6], a[7]));
    return u.s;
}

// ---- kernel 1: pack W -> bf16 B-fragments + one-time dtype probe ----
// pk slot = (nt*NCH + kk)*64 + lane ; lane=(q,n): B[k=kk*32+q*8+j][n=nt*16+n]
__global__ __launch_bounds__(256) void pack_w(const float* __restrict__ Wm,
                                              const int* __restrict__ voxel_idx,
                                              const int* __restrict__ num_list,
                                              int Bc,
                                              unsigned short* __restrict__ pk,
                                              int* __restrict__ flags) {
    const int t = threadIdx.x;
    if (blockIdx.x == 0 && t < 64) {
        int wv = voxel_idx[2 * t + 1];
        unsigned long long nz = __ballot(wv != 0);
        if (t == 0) {
            int f = (nz == 0ULL) ? 1 : 0;     // int64 voxel_idx -> odd words all zero
            bool n64 = false;
            if (Bc >= 2) {
                n64 = (num_list[1] == 0) && (num_list[0] != 0);
                if (Bc >= 4) n64 = n64 && (num_list[3] == 0);
            }
            if (n64) f |= 2;
            flags[0] = f;
        }
    }
    int slot = blockIdx.x * 256 + t;             // 0 .. NT*NCH*64-1 (27648)
    int l  = slot & 63;
    int kk = (slot >> 6) % NCH;
    int nt = slot / (64 * NCH);
    int q = l >> 4, n = l & 15;
    const float* src = Wm + (size_t)(kk * 32 + q * 8) * COUT + nt * 16 + n;
    short8 v;
    #pragma unroll
    for (int j = 0; j < 8; ++j)
        v[j] = (short)f2b(src[(size_t)j * COUT]);
    *(short8*)(pk + (size_t)slot * 8) = v;
}

// ---- kernel 2: barrier-free-k-loop fused gather + MFMA + LN + ReLU ----
__global__ __launch_bounds__(256) void dpc_mfma(
    const float* __restrict__ features,   // fp32 [N][CIN]
    const float* __restrict__ center,     // fp32 [M][3]
    const int* __restrict__ voxel_idx,    // int32/int64 (flags)
    const int* __restrict__ num_list,     // int32/int64 (flags)
    const unsigned short* __restrict__ pk,
    const int* __restrict__ flags,
    const float* __restrict__ gamma_,
    const float* __restrict__ beta_,
    float* __restrict__ out_feat,         // fp32 [Rtot][COUT]
    float* __restrict__ out_coor,         // fp32 [Rtot][4]
    int N, int M, int B, int K, int Rtot)
{
    __shared__ int   s_vid[TM][NK3];
    __shared__ int   s_src[TM];
    __shared__ int   s_valid[TM];
    __shared__ float s_c[TM][COUT + 4];

    const int t  = threadIdx.x;
    const int R0 = blockIdx.x * TM;

    const int fl = flags[0];              // uniform scalar load
    const bool vidx64 = (fl & 1) != 0;
    const bool nl64   = (fl & 2) != 0;

    // ---- preamble: per-row source index + validity ----
    if (t < TM) {
        int r = R0 + t;
        int src = 0, valid = 0;
        if (r < Rtot) {
            int b = r / K;
            int j = r - b * K;
            int offs = 0, nlb = 0;
            for (int i = 0; i < B; ++i) {
                int v = nl64 ? num_list[2 * i] : num_list[i];
                if (i < b) offs += v;
                if (i == b) nlb = v;
            }
            int end = nlb < K ? nlb : K;
            valid = (j < end) ? 1 : 0;
            src = offs + j;
            if (src < 0) src = 0;
            if (src > M - 1) src = M - 1;
        }
        s_src[t] = src;
        s_valid[t] = valid;
    }
    __syncthreads();

    // ---- coords output ----
    if (t < TM * 4) {
        int i = t >> 2, comp = t & 3;
        int r = R0 + i;
        if (r < Rtot) {
            float val;
            if (comp == 0) {
                int b = r / K;
                val = (b < B - 1) ? (float)(b + 1) : 0.0f;
            } else {
                val = s_valid[i] ? center[(size_t)s_src[i] * 3 + comp - 1] : 0.0f;
            }
            out_coor[(size_t)r * 4 + comp] = val;
        }
    }

    // ---- stage voxel ids (16 x 27, contiguous rows) ----
    for (int lin = t; lin < TM * NK3; lin += 256) {
        int i = lin / NK3;
        int k = lin - i * NK3;
        size_t e = (size_t)s_src[i] * NK3 + k;
        s_vid[i][k] = vidx64 ? voxel_idx[2 * e] : voxel_idx[e];
    }
    __syncthreads();   // last barrier before epilogue

    // ---- barrier-free K loop: per-lane direct A fragments from global ----
    const int lane = t & 63;
    const int w    = t >> 6;              // wave -> col tiles 2w, 2w+1
    const int m    = lane & 15;           // A row
    const int q    = lane >> 4;           // A k-quad
    const int nt0 = 2 * w, nt1 = 2 * w + 1;

    floatx4 acc0 = {0.f, 0.f, 0.f, 0.f};
    floatx4 acc1 = {0.f, 0.f, 0.f, 0.f};
    const short8 zero8 = {0, 0, 0, 0, 0, 0, 0, 0};

    float4 fa[2][2];
    bool   mneg[2];
    short8 bb[2][2];

    auto issueA = [&](int c, int sl) {
        int kc = c >> 1, half = c & 1;
        int idx = s_vid[m][kc];
        mneg[sl] = (idx < 0);
        int cl = idx < 0 ? 0 : (idx > N - 1 ? N - 1 : idx);
        const float* p = features + (size_t)cl * CIN + half * 32 + q * 8;
        fa[sl][0] = *(const float4*)p;
        fa[sl][1] = *(const float4*)(p + 4);
    };
    auto issueB = [&](int c, int sl) {
        bb[sl][0] = *(const short8*)(pk + ((size_t)(nt0 * NCH + c) * 64 + lane) * 8);
        bb[sl][1] = *(const short8*)(pk + ((size_t)(nt1 * NCH + c) * 64 + lane) * 8);
    };

    issueA(0, 0); issueB(0, 0);
    issueA(1, 1); issueB(1, 1);

    for (int c = 0; c < NCH; ++c) {
        const int sl = c & 1;
        float fbuf[8];
        *(float4*)fbuf       = fa[sl][0];
        *(float4*)(fbuf + 4) = fa[sl][1];
        short8 afr = mneg[sl] ? zero8 : cvt8(fbuf);
        short8 b0 = bb[sl][0], b1 = bb[sl][1];
        if (c + 2 < NCH) { issueA(c + 2, sl); issueB(c + 2, sl); }
        acc0 = __builtin_amdgcn_mfma_f32_16x16x32_bf16(afr, b0, acc0, 0, 0, 0);
        acc1 = __builtin_amdgcn_mfma_f32_16x16x32_bf16(afr, b1, acc1, 0, 0, 0);
    }

    // ---- C -> LDS (C/D layout: col=lane&15, row=(lane>>4)*4+reg) ----
    {
        const int cq = lane >> 4, n = lane & 15;
        #pragma unroll
        for (int reg = 0; reg < 4; ++reg) {
            s_c[cq * 4 + reg][nt0 * 16 + n] = acc0[reg];
            s_c[cq * 4 + reg][nt1 * 16 + n] = acc1[reg];
        }
    }
    __syncthreads();

    // ---- fused LayerNorm + ReLU epilogue ----
    const int h  = t >> 6;
    const int c2 = (t & 63) * 2;
    const float g0  = gamma_[c2];
    const float g1  = gamma_[c2 + 1];
    const float be0 = beta_[c2];
    const float be1 = beta_[c2 + 1];

    #pragma unroll
    for (int i = 0; i < 4; ++i) {
        int row = h * 4 + i;
        float a0 = s_c[row][c2];
        float a1 = s_c[row][c2 + 1];
        float s  = a0 + a1;
        float ss = a0 * a0 + a1 * a1;
        #pragma unroll
        for (int mm = 1; mm < 64; mm <<= 1) {
            s  += __shfl_xor(s,  mm, 64);
            ss += __shfl_xor(ss, mm, 64);
        }
        float mu   = s * (1.0f / COUT);
        float var  = ss * (1.0f / COUT) - mu * mu;
        float rstd = rsqrtf(var + EPS_LN);
        float v0 = (a0 - mu) * rstd * g0 + be0;
        float v1 = (a1 - mu) * rstd * g1 + be1;
        v0 = fmaxf(v0, 0.f);
        v1 = fmaxf(v1, 0.f);
        if (!s_valid[row]) { v0 = 0.f; v1 = 0.f; }
        int r = R0 + row;
        if (r < Rtot) {
            out_feat[(size_t)r * COUT + c2]     = v0;
            out_feat[(size_t)r * COUT + c2 + 1] = v1;
        }
    }
}

extern "C" void kernel_launch(void* const* d_in, const int* in_sizes, int n_in,
                              void* d_out, int out_size, void* d_ws, size_t ws_size,
                              hipStream_t stream) {
    const float* features = (const float*)d_in[0];
    const float* center   = (const float*)d_in[1];
    const int*   vidx     = (const int*)d_in[2];
    const int*   num_list = (const int*)d_in[3];
    const float* Wm       = (const float*)d_in[4];
    const float* gamma_   = (const float*)d_in[5];
    const float* beta_    = (const float*)d_in[6];

    const int B    = in_sizes[3];                 // 4
    const int Cout = in_sizes[5];                 // 128
    const int M    = in_sizes[1] / 3;             // 40000
    const int K3v  = in_sizes[2] / M;             // 27
    const int Cin  = (in_sizes[4] / Cout) / K3v;  // 64
    const int N    = in_sizes[0] / Cin;           // 200000
    const int Rtot = out_size / (Cout + 4);       // 8192
    const int K    = Rtot / B;                    // 2048

    float* out_feat = (float*)d_out;
    float* out_coor = out_feat + (size_t)Rtot * Cout;

    unsigned short* pk = (unsigned short*)d_ws;
    int* flags = (int*)((char*)d_ws + PK_BYTES);

    const int pack_grid = (NT * NCH * 64) / 256;        // 108
    pack_w<<<dim3(pack_grid), dim3(256), 0, stream>>>(Wm, vidx, num_list, B, pk, flags);

    const int tiles = (Rtot + TM - 1) / TM;             // 512
    dpc_mfma<<<dim3(tiles), dim3(256), 0, stream>>>(
        features, center, vidx, num_list, pk, flags, gamma_, beta_,
        out_feat, out_coor, N, M, B, K, Rtot);
}

// Round 9
// 127.979 us; speedup vs baseline: 6.8705x; 6.8705x over previous
//
#include <hip/hip_runtime.h>
#include <hip/hip_bf16.h>
#include <stdint.h>
#include <stddef.h>

#define TM 16      // output rows per tile (MFMA M)
#define CIN 64     // C_in
#define NK3 27     // K3 neighbors
#define COUT 128   // C_out
#define EPS_LN 1e-3f
#define NCH (NK3 * CIN / 32)     // 54 k-chunks of 32
#define NT  (COUT / 16)          // 8 column tiles
#define PK_BYTES (NT * NCH * 64 * 8 * 2)   // 442368

typedef __attribute__((ext_vector_type(8))) short   short8;   // MFMA A/B frag (8 bf16)
typedef __attribute__((ext_vector_type(4))) float   floatx4;  // MFMA C/D frag

__device__ __forceinline__ unsigned short f2b(float f) {
    union { float f; unsigned int i; } v;
    v.f = f;
    unsigned int i = v.i; // RNE bf16
    return (unsigned short)((i + 0x7fffu + ((i >> 16) & 1u)) >> 16);
}

// ---- kernel 1: pack W -> bf16 B-fragments + one-time dtype probe ----
__global__ __launch_bounds__(256) void pack_w(const float* __restrict__ Wm,
                                              const int* __restrict__ voxel_idx,
                                              const int* __restrict__ num_list,
                                              int Bc,
                                              unsigned short* __restrict__ pk,
                                              int* __restrict__ flags) {
    const int t = threadIdx.x;
    if (blockIdx.x == 0 && t < 64) {
        int wv = voxel_idx[2 * t + 1];
        unsigned long long nz = __ballot(wv != 0);
        if (t == 0) {
            int f = (nz == 0ULL) ? 1 : 0;     // int64 voxel_idx -> odd words all zero
            bool n64 = false;
            if (Bc >= 2) {
                n64 = (num_list[1] == 0) && (num_list[0] != 0);
                if (Bc >= 4) n64 = n64 && (num_list[3] == 0);
            }
            if (n64) f |= 2;
            flags[0] = f;
        }
    }
    int slot = blockIdx.x * 256 + t;             // 0 .. NT*NCH*64-1 (27648)
    int l  = slot & 63;
    int kk = (slot >> 6) % NCH;
    int nt = slot / (64 * NCH);
    int q = l >> 4, n = l & 15;
    const float* src = Wm + (size_t)(kk * 32 + q * 8) * COUT + nt * 16 + n;
    short8 v;
    #pragma unroll
    for (int j = 0; j < 8; ++j)
        v[j] = (short)f2b(src[(size_t)j * COUT]);
    *(short8*)(pk + (size_t)slot * 8) = v;
}

// ---- kernel 2: barrier-free k-loop, explicit register pipeline (no arrays) ----
__global__ __launch_bounds__(256) void dpc_mfma(
    const float* __restrict__ features,   // fp32 [N][CIN]
    const float* __restrict__ center,     // fp32 [M][3]
    const int* __restrict__ voxel_idx,    // int32/int64 (flags)
    const int* __restrict__ num_list,     // int32/int64 (flags)
    const unsigned short* __restrict__ pk,
    const int* __restrict__ flags,
    const float* __restrict__ gamma_,
    const float* __restrict__ beta_,
    float* __restrict__ out_feat,         // fp32 [Rtot][COUT]
    float* __restrict__ out_coor,         // fp32 [Rtot][4]
    int N, int M, int B, int K, int Rtot)
{
    __shared__ int   s_vid[TM][NK3];
    __shared__ int   s_src[TM];
    __shared__ int   s_valid[TM];
    __shared__ float s_c[TM][COUT + 4];

    const int t  = threadIdx.x;
    const int R0 = blockIdx.x * TM;

    const int fl = flags[0];              // uniform scalar load
    const bool vidx64 = (fl & 1) != 0;
    const bool nl64   = (fl & 2) != 0;

    // ---- preamble: per-row source index + validity ----
    if (t < TM) {
        int r = R0 + t;
        int src = 0, valid = 0;
        if (r < Rtot) {
            int b = r / K;
            int j = r - b * K;
            int offs = 0, nlb = 0;
            for (int i = 0; i < B; ++i) {
                int v = nl64 ? num_list[2 * i] : num_list[i];
                if (i < b) offs += v;
                if (i == b) nlb = v;
            }
            int end = nlb < K ? nlb : K;
            valid = (j < end) ? 1 : 0;
            src = offs + j;
            if (src < 0) src = 0;
            if (src > M - 1) src = M - 1;
        }
        s_src[t] = src;
        s_valid[t] = valid;
    }
    __syncthreads();

    // ---- coords output ----
    if (t < TM * 4) {
        int i = t >> 2, comp = t & 3;
        int r = R0 + i;
        if (r < Rtot) {
            float val;
            if (comp == 0) {
                int b = r / K;
                val = (b < B - 1) ? (float)(b + 1) : 0.0f;
            } else {
                val = s_valid[i] ? center[(size_t)s_src[i] * 3 + comp - 1] : 0.0f;
            }
            out_coor[(size_t)r * 4 + comp] = val;
        }
    }

    // ---- stage voxel ids (16 x 27) ----
    for (int lin = t; lin < TM * NK3; lin += 256) {
        int i = lin / NK3;
        int k = lin - i * NK3;
        size_t e = (size_t)s_src[i] * NK3 + k;
        s_vid[i][k] = vidx64 ? voxel_idx[2 * e] : voxel_idx[e];
    }
    __syncthreads();   // last barrier before epilogue

    // ---- barrier-free K loop ----
    const int lane = t & 63;
    const int w    = t >> 6;              // wave -> col tiles 2w, 2w+1
    const int m    = lane & 15;           // A row
    const int q    = lane >> 4;           // A k-quad
    const int nt0 = 2 * w, nt1 = 2 * w + 1;

    floatx4 acc0 = {0.f, 0.f, 0.f, 0.f};
    floatx4 acc1 = {0.f, 0.f, 0.f, 0.f};

    // explicit pipeline stage registers (NO arrays -> no scratch demotion)
    float4 pa0, pa1, qa0, qa1;            // A stage 0 / stage 1
    bool   pneg, qneg;
    short8 pb0, pb1, qb0, qb1;            // B stage 0 / stage 1

#define LOAD_A(c, r0, r1, neg)                                            \
    {                                                                     \
        int kc_ = (c) >> 1, half_ = (c) & 1;                              \
        int idx_ = s_vid[m][kc_];                                         \
        neg = (idx_ < 0);                                                 \
        int cl_ = idx_ < 0 ? 0 : (idx_ > N - 1 ? N - 1 : idx_);           \
        const float* p_ = features + (size_t)cl_ * CIN + half_ * 32 + q * 8; \
        r0 = *(const float4*)p_;                                          \
        r1 = *(const float4*)(p_ + 4);                                    \
    }
#define LOAD_B(c, b0, b1)                                                 \
    {                                                                     \
        b0 = *(const short8*)(pk + ((size_t)(nt0 * NCH + (c)) * 64 + lane) * 8); \
        b1 = *(const short8*)(pk + ((size_t)(nt1 * NCH + (c)) * 64 + lane) * 8); \
    }
#define MAKE_A(afr, r0, r1, neg)                                          \
    short8 afr;                                                           \
    {                                                                     \
        union { __hip_bfloat162 h[4]; short8 s; } u_;                     \
        u_.h[0] = __float22bfloat162_rn(make_float2(r0.x, r0.y));         \
        u_.h[1] = __float22bfloat162_rn(make_float2(r0.z, r0.w));         \
        u_.h[2] = __float22bfloat162_rn(make_float2(r1.x, r1.y));         \
        u_.h[3] = __float22bfloat162_rn(make_float2(r1.z, r1.w));         \
        const short8 z8_ = {0, 0, 0, 0, 0, 0, 0, 0};                      \
        afr = neg ? z8_ : u_.s;                                           \
    }

    LOAD_A(0, pa0, pa1, pneg); LOAD_B(0, pb0, pb1);
    LOAD_A(1, qa0, qa1, qneg); LOAD_B(1, qb0, qb1);

    #pragma unroll
    for (int cp = 0; cp < NCH / 2; ++cp) {
        const int c0 = 2 * cp;
        // chunk c0 from stage-p registers; refill stage p with chunk c0+2
        {
            MAKE_A(afr, pa0, pa1, pneg);
            short8 tb0 = pb0, tb1 = pb1;
            if (c0 + 2 < NCH) { LOAD_A(c0 + 2, pa0, pa1, pneg); LOAD_B(c0 + 2, pb0, pb1); }
            acc0 = __builtin_amdgcn_mfma_f32_16x16x32_bf16(afr, tb0, acc0, 0, 0, 0);
            acc1 = __builtin_amdgcn_mfma_f32_16x16x32_bf16(afr, tb1, acc1, 0, 0, 0);
        }
        // chunk c0+1 from stage-q registers; refill stage q with chunk c0+3
        {
            MAKE_A(afr, qa0, qa1, qneg);
            short8 tb0 = qb0, tb1 = qb1;
            if (c0 + 3 < NCH) { LOAD_A(c0 + 3, qa0, qa1, qneg); LOAD_B(c0 + 3, qb0, qb1); }
            acc0 = __builtin_amdgcn_mfma_f32_16x16x32_bf16(afr, tb0, acc0, 0, 0, 0);
            acc1 = __builtin_amdgcn_mfma_f32_16x16x32_bf16(afr, tb1, acc1, 0, 0, 0);
        }
    }
#undef LOAD_A
#undef LOAD_B
#undef MAKE_A

    // ---- C -> LDS (C/D layout: col=lane&15, row=(lane>>4)*4+reg) ----
    {
        const int cq = lane >> 4, n = lane & 15;
        #pragma unroll
        for (int reg = 0; reg < 4; ++reg) {
            s_c[cq * 4 + reg][nt0 * 16 + n] = acc0[reg];
            s_c[cq * 4 + reg][nt1 * 16 + n] = acc1[reg];
        }
    }
    __syncthreads();

    // ---- fused LayerNorm + ReLU epilogue ----
    const int h  = t >> 6;
    const int c2 = (t & 63) * 2;
    const float g0  = gamma_[c2];
    const float g1  = gamma_[c2 + 1];
    const float be0 = beta_[c2];
    const float be1 = beta_[c2 + 1];

    #pragma unroll
    for (int i = 0; i < 4; ++i) {
        int row = h * 4 + i;
        float a0 = s_c[row][c2];
        float a1 = s_c[row][c2 + 1];
        float s  = a0 + a1;
        float ss = a0 * a0 + a1 * a1;
        #pragma unroll
        for (int mm = 1; mm < 64; mm <<= 1) {
            s  += __shfl_xor(s,  mm, 64);
            ss += __shfl_xor(ss, mm, 64);
        }
        float mu   = s * (1.0f / COUT);
        float var  = ss * (1.0f / COUT) - mu * mu;
        float rstd = rsqrtf(var + EPS_LN);
        float v0 = (a0 - mu) * rstd * g0 + be0;
        float v1 = (a1 - mu) * rstd * g1 + be1;
        v0 = fmaxf(v0, 0.f);
        v1 = fmaxf(v1, 0.f);
        if (!s_valid[row]) { v0 = 0.f; v1 = 0.f; }
        int r = R0 + row;
        if (r < Rtot) {
            out_feat[(size_t)r * COUT + c2]     = v0;
            out_feat[(size_t)r * COUT + c2 + 1] = v1;
        }
    }
}

extern "C" void kernel_launch(void* const* d_in, const int* in_sizes, int n_in,
                              void* d_out, int out_size, void* d_ws, size_t ws_size,
                              hipStream_t stream) {
    const float* features = (const float*)d_in[0];
    const float* center   = (const float*)d_in[1];
    const int*   vidx     = (const int*)d_in[2];
    const int*   num_list = (const int*)d_in[3];
    const float* Wm       = (const float*)d_in[4];
    const float* gamma_   = (const float*)d_in[5];
    const float* beta_    = (const float*)d_in[6];

    const int B    = in_sizes[3];                 // 4
    const int Cout = in_sizes[5];                 // 128
    const int M    = in_sizes[1] / 3;             // 40000
    const int K3v  = in_sizes[2] / M;             // 27
    const int Cin  = (in_sizes[4] / Cout) / K3v;  // 64
    const int N    = in_sizes[0] / Cin;           // 200000
    const int Rtot = out_size / (Cout + 4);       // 8192
    const int K    = Rtot / B;                    // 2048

    float* out_feat = (float*)d_out;
    float* out_coor = out_feat + (size_t)Rtot * Cout;

    unsigned short* pk = (unsigned short*)d_ws;
    int* flags = (int*)((char*)d_ws + PK_BYTES);

    const int pack_grid = (NT * NCH * 64) / 256;        // 108
    pack_w<<<dim3(pack_grid), dim3(256), 0, stream>>>(Wm, vidx, num_list, B, pk, flags);

    const int tiles = (Rtot + TM - 1) / TM;             // 512
    dpc_mfma<<<dim3(tiles), dim3(256), 0, stream>>>(
        features, center, vidx, num_list, pk, flags, gamma_, beta_,
        out_feat, out_coor, N, M, B, K, Rtot);
}

// Round 10
// 112.241 us; speedup vs baseline: 7.8339x; 1.1402x over previous
//
#include <hip/hip_runtime.h>
#include <hip/hip_bf16.h>
#include <stdint.h>
#include <stddef.h>

#define TM 16      // output rows per block
#define CIN 64     // C_in
#define NK3 27     // K3 neighbors
#define NK3P 28    // padded to even (kc=27 contributes zero)
#define COUT 128   // C_out
#define EPS_LN 1e-3f
#define KCH  (NK3 * CIN / 32)    // 54 real k-chunks of 32
#define KCHP (NK3P * CIN / 32)   // 56 padded k-chunks
#define NT   (COUT / 16)         // 8 column tiles
#define NPAIR (NK3P / 2)         // 14 kc-pairs
#define PK_BYTES (NT * KCHP * 64 * 8 * 2)   // 458752

typedef __attribute__((ext_vector_type(8))) short   short8;   // MFMA A/B frag (8 bf16)
typedef __attribute__((ext_vector_type(4))) float   floatx4;  // MFMA C/D frag
typedef __attribute__((ext_vector_type(4))) unsigned short ushort4v;

__device__ __forceinline__ unsigned short f2b(float f) {
    union { float f; unsigned int i; } v;
    v.f = f;
    unsigned int i = v.i; // RNE bf16
    return (unsigned short)((i + 0x7fffu + ((i >> 16) & 1u)) >> 16);
}

// ---- kernel 1: pack W -> bf16 B-fragments (zero-padded) + one-time dtype probe ----
__global__ __launch_bounds__(256) void pack_w(const float* __restrict__ Wm,
                                              const int* __restrict__ voxel_idx,
                                              const int* __restrict__ num_list,
                                              int Bc,
                                              unsigned short* __restrict__ pk,
                                              int* __restrict__ flags) {
    const int t = threadIdx.x;
    if (blockIdx.x == 0 && t < 64) {
        int wv = voxel_idx[2 * t + 1];
        unsigned long long nz = __ballot(wv != 0);
        if (t == 0) {
            int f = (nz == 0ULL) ? 1 : 0;     // int64 voxel_idx -> odd words all zero
            bool n64 = false;
            if (Bc >= 2) {
                n64 = (num_list[1] == 0) && (num_list[0] != 0);
                if (Bc >= 4) n64 = n64 && (num_list[3] == 0);
            }
            if (n64) f |= 2;
            flags[0] = f;
        }
    }
    int slot = blockIdx.x * 256 + t;             // 0 .. NT*KCHP*64-1
    int l  = slot & 63;
    int kk = (slot >> 6) % KCHP;
    int nt = slot / (64 * KCHP);
    short8 v = {0, 0, 0, 0, 0, 0, 0, 0};
    if (kk < KCH) {
        int q = l >> 4, n = l & 15;
        const float* src = Wm + (size_t)(kk * 32 + q * 8) * COUT + nt * 16 + n;
        #pragma unroll
        for (int j = 0; j < 8; ++j)
            v[j] = (short)f2b(src[(size_t)j * COUT]);
    }
    *(short8*)(pk + (size_t)slot * 8) = v;
}

// ---- kernel 2: r6 structure + tri-buffered LDS, gather distance 2 pairs ----
__global__ __launch_bounds__(256) void dpc_mfma(
    const float* __restrict__ features,   // fp32 [N][CIN]
    const float* __restrict__ center,     // fp32 [M][3]
    const int* __restrict__ voxel_idx,    // int32/int64 (flags)
    const int* __restrict__ num_list,     // int32/int64 (flags)
    const unsigned short* __restrict__ pk,
    const int* __restrict__ flags,
    const float* __restrict__ gamma_,
    const float* __restrict__ beta_,
    float* __restrict__ out_feat,         // fp32 [Rtot][COUT]
    float* __restrict__ out_coor,         // fp32 [Rtot][4]
    int N, int M, int B, int K, int Rtot)
{
    __shared__ int s_vid[TM][NK3P];
    __shared__ int s_src[TM];
    __shared__ int s_valid[TM];
    __shared__ __align__(16) unsigned short s_a[3][2048]; // tri-buffer, pair slabs
    __shared__ float s_c[TM][COUT + 4];

    const int t  = threadIdx.x;
    const int R0 = blockIdx.x * TM;

    const int fl = flags[0];              // uniform scalar load (no serial probe)
    const bool vidx64 = (fl & 1) != 0;
    const bool nl64   = (fl & 2) != 0;

    // ---- preamble: per-row source index + validity ----
    if (t < TM) {
        int r = R0 + t;
        int src = 0, valid = 0;
        if (r < Rtot) {
            int b = r / K;
            int j = r - b * K;
            int offs = 0, nlb = 0;
            for (int i = 0; i < B; ++i) {
                int v = nl64 ? num_list[2 * i] : num_list[i];
                if (i < b) offs += v;
                if (i == b) nlb = v;
            }
            int end = nlb < K ? nlb : K;
            valid = (j < end) ? 1 : 0;
            src = offs + j;
            if (src < 0) src = 0;
            if (src > M - 1) src = M - 1;
        }
        s_src[t] = src;
        s_valid[t] = valid;
    }
    __syncthreads();

    // ---- coords output ----
    if (t < TM * 4) {
        int i = t >> 2, comp = t & 3;
        int r = R0 + i;
        if (r < Rtot) {
            float val;
            if (comp == 0) {
                int b = r / K;
                val = (b < B - 1) ? (float)(b + 1) : 0.0f;
            } else {
                val = s_valid[i] ? center[(size_t)s_src[i] * 3 + comp - 1] : 0.0f;
            }
            out_coor[(size_t)r * 4 + comp] = val;
        }
    }

    // ---- stage voxel ids (pad kc=27 with -1 -> zero A fragment) ----
    for (int lin = t; lin < TM * NK3P; lin += 256) {
        int i = lin / NK3P;
        int k = lin - i * NK3P;
        int v = -1;
        if (k < NK3) {
            size_t e = (size_t)s_src[i] * NK3 + k;
            v = vidx64 ? voxel_idx[2 * e] : voxel_idx[e];
        }
        s_vid[i][k] = v;
    }
    __syncthreads();

    // ---- staging geometry (verified r5/r6): thread t -> row m, cols c0..c0+3 ----
    const int m  = t >> 4;
    const int c0 = (t & 15) * 4;
    const int chunk = c0 >> 5;
    const int q4    = (c0 & 31) >> 3;
    const int j0    = c0 & 7;
    const int aoff  = chunk * 512 + (q4 * 16 + m) * 8 + j0;

    auto gatherf4 = [&](int kc) -> float4 {
        int idx = s_vid[m][kc];
        float4 r = make_float4(0.f, 0.f, 0.f, 0.f);
        if (idx >= 0) {
            if (idx > N - 1) idx = N - 1;
            r = *(const float4*)(features + (size_t)idx * CIN + c0);
        }
        return r;
    };
    auto stash = [&](int buf, int sub, float4 v) {
        ushort4v u;
        u[0] = f2b(v.x); u[1] = f2b(v.y); u[2] = f2b(v.z); u[3] = f2b(v.w);
        *(ushort4v*)&s_a[buf][sub * 1024 + aoff] = u;
    };

    const int w    = t >> 6;
    const int lane = t & 63;
    const int nt0 = 2 * w, nt1 = 2 * w + 1;
    auto loadB = [&](int nt, int kk) -> short8 {
        return *(const short8*)(pk + ((size_t)(nt * KCHP + kk) * 64 + lane) * 8);
    };

    floatx4 acc0 = {0.f, 0.f, 0.f, 0.f};
    floatx4 acc1 = {0.f, 0.f, 0.f, 0.f};

    // ---- prologue: pair0 -> buf0; pair1 gathered into regs; B(pair0) loaded ----
    stash(0, 0, gatherf4(0));
    stash(0, 1, gatherf4(1));
    float4 cA0 = gatherf4(2);            // stage C = pair 1 (explicit scalars)
    float4 cA1 = gatherf4(3);
    short8 bb[8];
    #pragma unroll
    for (int c = 0; c < 4; ++c) {
        bb[2 * c]     = loadB(nt0, c);
        bb[2 * c + 1] = loadB(nt1, c);
    }
    __syncthreads();

    for (int p = 0; p < NPAIR; ++p) {
        const bool hasC = (p + 1 < NPAIR);   // pair p+1 exists (stage C)
        const bool hasN = (p + 2 < NPAIR);   // pair p+2 exists (stage N)

        // issue gathers for pair p+2 (drained 2 bodies later)
        float4 nA0, nA1;
        if (hasN) { nA0 = gatherf4(2 * p + 4); nA1 = gatherf4(2 * p + 5); }
        // B register pipeline, 1 pair ahead (L2-resident)
        short8 nb[8];
        if (hasC) {
            const int kk = 4 * (p + 1);
            #pragma unroll
            for (int c = 0; c < 4; ++c) {
                nb[2 * c]     = loadB(nt0, kk + c);
                nb[2 * c + 1] = loadB(nt1, kk + c);
            }
        }

        // A fragments from buf p%3 (conflict-free ds_read_b128)
        const int buf = p % 3;
        const short8 a0 = *(const short8*)&s_a[buf][       lane * 8];
        const short8 a1 = *(const short8*)&s_a[buf][ 512 + lane * 8];
        const short8 a2 = *(const short8*)&s_a[buf][1024 + lane * 8];
        const short8 a3 = *(const short8*)&s_a[buf][1536 + lane * 8];

        acc0 = __builtin_amdgcn_mfma_f32_16x16x32_bf16(a0, bb[0], acc0, 0, 0, 0);
        acc1 = __builtin_amdgcn_mfma_f32_16x16x32_bf16(a0, bb[1], acc1, 0, 0, 0);
        acc0 = __builtin_amdgcn_mfma_f32_16x16x32_bf16(a1, bb[2], acc0, 0, 0, 0);
        acc1 = __builtin_amdgcn_mfma_f32_16x16x32_bf16(a1, bb[3], acc1, 0, 0, 0);
        acc0 = __builtin_amdgcn_mfma_f32_16x16x32_bf16(a2, bb[4], acc0, 0, 0, 0);
        acc1 = __builtin_amdgcn_mfma_f32_16x16x32_bf16(a2, bb[5], acc1, 0, 0, 0);
        acc0 = __builtin_amdgcn_mfma_f32_16x16x32_bf16(a3, bb[6], acc0, 0, 0, 0);
        acc1 = __builtin_amdgcn_mfma_f32_16x16x32_bf16(a3, bb[7], acc1, 0, 0, 0);

        // stash pair p+1 (issued one full iteration ago) into buf (p+1)%3
        if (hasC) {
            const int wb = (p + 1) % 3;
            stash(wb, 0, cA0);
            stash(wb, 1, cA1);
        }
        __syncthreads();
        if (hasC) {
            #pragma unroll
            for (int i = 0; i < 8; ++i) bb[i] = nb[i];
        }
        if (hasN) { cA0 = nA0; cA1 = nA1; }
    }

    // ---- C -> LDS (C/D layout: col=lane&15, row=(lane>>4)*4+reg) ----
    {
        const int cq = lane >> 4, n = lane & 15;
        #pragma unroll
        for (int reg = 0; reg < 4; ++reg) {
            s_c[cq * 4 + reg][nt0 * 16 + n] = acc0[reg];
            s_c[cq * 4 + reg][nt1 * 16 + n] = acc1[reg];
        }
    }
    __syncthreads();

    // ---- fused LayerNorm + ReLU epilogue ----
    const int h  = t >> 6;
    const int c2 = (t & 63) * 2;
    const float g0  = gamma_[c2];
    const float g1  = gamma_[c2 + 1];
    const float be0 = beta_[c2];
    const float be1 = beta_[c2 + 1];

    #pragma unroll
    for (int i = 0; i < 4; ++i) {
        int row = h * 4 + i;
        float a0 = s_c[row][c2];
        float a1 = s_c[row][c2 + 1];
        float s  = a0 + a1;
        float ss = a0 * a0 + a1 * a1;
        #pragma unroll
        for (int mm = 1; mm < 64; mm <<= 1) {
            s  += __shfl_xor(s,  mm, 64);
            ss += __shfl_xor(ss, mm, 64);
        }
        float mu   = s * (1.0f / COUT);
        float var  = ss * (1.0f / COUT) - mu * mu;
        float rstd = rsqrtf(var + EPS_LN);
        float v0 = (a0 - mu) * rstd * g0 + be0;
        float v1 = (a1 - mu) * rstd * g1 + be1;
        v0 = fmaxf(v0, 0.f);
        v1 = fmaxf(v1, 0.f);
        if (!s_valid[row]) { v0 = 0.f; v1 = 0.f; }
        int r = R0 + row;
        if (r < Rtot) {
            out_feat[(size_t)r * COUT + c2]     = v0;
            out_feat[(size_t)r * COUT + c2 + 1] = v1;
        }
    }
}

extern "C" void kernel_launch(void* const* d_in, const int* in_sizes, int n_in,
                              void* d_out, int out_size, void* d_ws, size_t ws_size,
                              hipStream_t stream) {
    const float* features = (const float*)d_in[0];
    const float* center   = (const float*)d_in[1];
    const int*   vidx     = (const int*)d_in[2];
    const int*   num_list = (const int*)d_in[3];
    const float* Wm       = (const float*)d_in[4];
    const float* gamma_   = (const float*)d_in[5];
    const float* beta_    = (const float*)d_in[6];

    const int B    = in_sizes[3];                 // 4
    const int Cout = in_sizes[5];                 // 128
    const int M    = in_sizes[1] / 3;             // 40000
    const int K3v  = in_sizes[2] / M;             // 27
    const int Cin  = (in_sizes[4] / Cout) / K3v;  // 64
    const int N    = in_sizes[0] / Cin;           // 200000
    const int Rtot = out_size / (Cout + 4);       // 8192
    const int K    = Rtot / B;                    // 2048

    float* out_feat = (float*)d_out;
    float* out_coor = out_feat + (size_t)Rtot * Cout;

    unsigned short* pk = (unsigned short*)d_ws;
    int* flags = (int*)((char*)d_ws + PK_BYTES);

    const int pack_grid = (NT * KCHP * 64) / 256;       // 112
    pack_w<<<dim3(pack_grid), dim3(256), 0, stream>>>(Wm, vidx, num_list, B, pk, flags);

    const int tiles = (Rtot + TM - 1) / TM;             // 512
    dpc_mfma<<<dim3(tiles), dim3(256), 0, stream>>>(
        features, center, vidx, num_list, pk, flags, gamma_, beta_,
        out_feat, out_coor, N, M, B, K, Rtot);
}

// Round 11
// 110.429 us; speedup vs baseline: 7.9624x; 1.0164x over previous
//
#include <hip/hip_runtime.h>
#include <hip/hip_bf16.h>
#include <stdint.h>
#include <stddef.h>

#define TM 16      // output rows per block
#define CIN 64     // C_in
#define NK3 27     // K3 neighbors
#define NK3P 28    // padded to even (kc=27 contributes zero)
#define COUT 128   // C_out
#define EPS_LN 1e-3f
#define KCH  (NK3 * CIN / 32)    // 54 real k-chunks of 32
#define KCHP (NK3P * CIN / 32)   // 56 padded k-chunks
#define NT   (COUT / 16)         // 8 column tiles (one per wave now)
#define NPAIR (NK3P / 2)         // 14 kc-pairs
#define PK_BYTES (NT * KCHP * 64 * 8 * 2)   // 458752

typedef __attribute__((ext_vector_type(8))) short   short8;   // MFMA A/B frag (8 bf16)
typedef __attribute__((ext_vector_type(4))) float   floatx4;  // MFMA C/D frag
typedef __attribute__((ext_vector_type(4))) unsigned short ushort4v;

__device__ __forceinline__ unsigned short f2b(float f) {
    union { float f; unsigned int i; } v;
    v.f = f;
    unsigned int i = v.i; // RNE bf16
    return (unsigned short)((i + 0x7fffu + ((i >> 16) & 1u)) >> 16);
}

// ---- kernel 1: pack W -> bf16 B-fragments (zero-padded) + one-time dtype probe ----
__global__ __launch_bounds__(256) void pack_w(const float* __restrict__ Wm,
                                              const int* __restrict__ voxel_idx,
                                              const int* __restrict__ num_list,
                                              int Bc,
                                              unsigned short* __restrict__ pk,
                                              int* __restrict__ flags) {
    const int t = threadIdx.x;
    if (blockIdx.x == 0 && t < 64) {
        int wv = voxel_idx[2 * t + 1];
        unsigned long long nz = __ballot(wv != 0);
        if (t == 0) {
            int f = (nz == 0ULL) ? 1 : 0;     // int64 voxel_idx -> odd words all zero
            bool n64 = false;
            if (Bc >= 2) {
                n64 = (num_list[1] == 0) && (num_list[0] != 0);
                if (Bc >= 4) n64 = n64 && (num_list[3] == 0);
            }
            if (n64) f |= 2;
            flags[0] = f;
        }
    }
    int slot = blockIdx.x * 256 + t;             // 0 .. NT*KCHP*64-1
    int l  = slot & 63;
    int kk = (slot >> 6) % KCHP;
    int nt = slot / (64 * KCHP);
    short8 v = {0, 0, 0, 0, 0, 0, 0, 0};
    if (kk < KCH) {
        int q = l >> 4, n = l & 15;
        const float* src = Wm + (size_t)(kk * 32 + q * 8) * COUT + nt * 16 + n;
        #pragma unroll
        for (int j = 0; j < 8; ++j)
            v[j] = (short)f2b(src[(size_t)j * COUT]);
    }
    *(short8*)(pk + (size_t)slot * 8) = v;
}

// ---- kernel 2: r10 structure at 8 waves/block (16 waves/CU), wave-per-col-tile ----
__global__ __launch_bounds__(512) void dpc_mfma(
    const float* __restrict__ features,   // fp32 [N][CIN]
    const float* __restrict__ center,     // fp32 [M][3]
    const int* __restrict__ voxel_idx,    // int32/int64 (flags)
    const int* __restrict__ num_list,     // int32/int64 (flags)
    const unsigned short* __restrict__ pk,
    const int* __restrict__ flags,
    const float* __restrict__ gamma_,
    const float* __restrict__ beta_,
    float* __restrict__ out_feat,         // fp32 [Rtot][COUT]
    float* __restrict__ out_coor,         // fp32 [Rtot][4]
    int N, int M, int B, int K, int Rtot)
{
    __shared__ int s_vid[TM][NK3P];
    __shared__ int s_src[TM];
    __shared__ int s_valid[TM];
    __shared__ __align__(16) unsigned short s_a[3][2048]; // tri-buffer, pair slabs
    __shared__ float s_c[TM][COUT + 4];

    const int t  = threadIdx.x;
    const int R0 = blockIdx.x * TM;

    const int fl = flags[0];              // uniform scalar load
    const bool vidx64 = (fl & 1) != 0;
    const bool nl64   = (fl & 2) != 0;

    // ---- preamble: per-row source index + validity ----
    if (t < TM) {
        int r = R0 + t;
        int src = 0, valid = 0;
        if (r < Rtot) {
            int b = r / K;
            int j = r - b * K;
            int offs = 0, nlb = 0;
            for (int i = 0; i < B; ++i) {
                int v = nl64 ? num_list[2 * i] : num_list[i];
                if (i < b) offs += v;
                if (i == b) nlb = v;
            }
            int end = nlb < K ? nlb : K;
            valid = (j < end) ? 1 : 0;
            src = offs + j;
            if (src < 0) src = 0;
            if (src > M - 1) src = M - 1;
        }
        s_src[t] = src;
        s_valid[t] = valid;
    }
    __syncthreads();

    // ---- coords output ----
    if (t < TM * 4) {
        int i = t >> 2, comp = t & 3;
        int r = R0 + i;
        if (r < Rtot) {
            float val;
            if (comp == 0) {
                int b = r / K;
                val = (b < B - 1) ? (float)(b + 1) : 0.0f;
            } else {
                val = s_valid[i] ? center[(size_t)s_src[i] * 3 + comp - 1] : 0.0f;
            }
            out_coor[(size_t)r * 4 + comp] = val;
        }
    }

    // ---- stage voxel ids (pad kc=27 with -1 -> zero A fragment) ----
    for (int lin = t; lin < TM * NK3P; lin += 512) {
        int i = lin / NK3P;
        int k = lin - i * NK3P;
        int v = -1;
        if (k < NK3) {
            size_t e = (size_t)s_src[i] * NK3 + k;
            v = vidx64 ? voxel_idx[2 * e] : voxel_idx[e];
        }
        s_vid[i][k] = v;
    }
    __syncthreads();

    // ---- staging geometry: thread t stages ONE float4 of its pair ----
    const int sub = t >> 8;               // which kc of the pair (0/1)
    const int rem = t & 255;
    const int m   = rem >> 4;             // row 0..15
    const int c0  = (rem & 15) * 4;       // cin col base
    const int chunk = c0 >> 5;
    const int q4    = (c0 & 31) >> 3;
    const int j0    = c0 & 7;
    const int aoff  = sub * 1024 + chunk * 512 + (q4 * 16 + m) * 8 + j0;

    auto gatherPair = [&](int p) -> float4 {   // gathers this thread's kc of pair p
        int idx = s_vid[m][2 * p + sub];
        float4 r = make_float4(0.f, 0.f, 0.f, 0.f);
        if (idx >= 0) {
            if (idx > N - 1) idx = N - 1;
            r = *(const float4*)(features + (size_t)idx * CIN + c0);
        }
        return r;
    };
    auto stash = [&](int buf, float4 v) {
        ushort4v u;
        u[0] = f2b(v.x); u[1] = f2b(v.y); u[2] = f2b(v.z); u[3] = f2b(v.w);
        *(ushort4v*)&s_a[buf][aoff] = u;
    };

    const int w    = t >> 6;              // wave 0..7 -> col tile nt = w
    const int lane = t & 63;
    auto loadB = [&](int kk) -> short8 {
        return *(const short8*)(pk + ((size_t)(w * KCHP + kk) * 64 + lane) * 8);
    };

    floatx4 acc = {0.f, 0.f, 0.f, 0.f};

    // ---- prologue: pair0 -> buf0; pair1 in regs; B(pair0) in regs ----
    stash(0, gatherPair(0));
    float4 cA = gatherPair(1);
    short8 bb0 = loadB(0), bb1 = loadB(1), bb2 = loadB(2), bb3 = loadB(3);
    __syncthreads();

    for (int p = 0; p < NPAIR; ++p) {
        const bool hasC = (p + 1 < NPAIR);
        const bool hasN = (p + 2 < NPAIR);

        float4 nA;
        if (hasN) nA = gatherPair(p + 2);         // drained 2 bodies later
        short8 nb0, nb1, nb2, nb3;
        if (hasC) {
            const int kk = 4 * (p + 1);
            nb0 = loadB(kk); nb1 = loadB(kk + 1); nb2 = loadB(kk + 2); nb3 = loadB(kk + 3);
        }

        const int buf = p % 3;
        const short8 a0 = *(const short8*)&s_a[buf][       lane * 8];
        const short8 a1 = *(const short8*)&s_a[buf][ 512 + lane * 8];
        const short8 a2 = *(const short8*)&s_a[buf][1024 + lane * 8];
        const short8 a3 = *(const short8*)&s_a[buf][1536 + lane * 8];

        acc = __builtin_amdgcn_mfma_f32_16x16x32_bf16(a0, bb0, acc, 0, 0, 0);
        acc = __builtin_amdgcn_mfma_f32_16x16x32_bf16(a1, bb1, acc, 0, 0, 0);
        acc = __builtin_amdgcn_mfma_f32_16x16x32_bf16(a2, bb2, acc, 0, 0, 0);
        acc = __builtin_amdgcn_mfma_f32_16x16x32_bf16(a3, bb3, acc, 0, 0, 0);

        if (hasC) stash((p + 1) % 3, cA);
        __syncthreads();
        if (hasC) { bb0 = nb0; bb1 = nb1; bb2 = nb2; bb3 = nb3; }
        if (hasN) cA = nA;
    }

    // ---- C -> LDS (C/D layout: col=lane&15, row=(lane>>4)*4+reg) ----
    {
        const int cq = lane >> 4, n = lane & 15;
        #pragma unroll
        for (int reg = 0; reg < 4; ++reg)
            s_c[cq * 4 + reg][w * 16 + n] = acc[reg];
    }
    __syncthreads();

    // ---- fused LayerNorm + ReLU epilogue (2 rows per wave) ----
    const int c2 = lane * 2;
    const float g0  = gamma_[c2];
    const float g1  = gamma_[c2 + 1];
    const float be0 = beta_[c2];
    const float be1 = beta_[c2 + 1];

    #pragma unroll
    for (int i = 0; i < 2; ++i) {
        int row = w * 2 + i;
        float a0 = s_c[row][c2];
        float a1 = s_c[row][c2 + 1];
        float s  = a0 + a1;
        float ss = a0 * a0 + a1 * a1;
        #pragma unroll
        for (int mm = 1; mm < 64; mm <<= 1) {
            s  += __shfl_xor(s,  mm, 64);
            ss += __shfl_xor(ss, mm, 64);
        }
        float mu   = s * (1.0f / COUT);
        float var  = ss * (1.0f / COUT) - mu * mu;
        float rstd = rsqrtf(var + EPS_LN);
        float v0 = (a0 - mu) * rstd * g0 + be0;
        float v1 = (a1 - mu) * rstd * g1 + be1;
        v0 = fmaxf(v0, 0.f);
        v1 = fmaxf(v1, 0.f);
        if (!s_valid[row]) { v0 = 0.f; v1 = 0.f; }
        int r = R0 + row;
        if (r < Rtot) {
            out_feat[(size_t)r * COUT + c2]     = v0;
            out_feat[(size_t)r * COUT + c2 + 1] = v1;
        }
    }
}

extern "C" void kernel_launch(void* const* d_in, const int* in_sizes, int n_in,
                              void* d_out, int out_size, void* d_ws, size_t ws_size,
                              hipStream_t stream) {
    const float* features = (const float*)d_in[0];
    const float* center   = (const float*)d_in[1];
    const int*   vidx     = (const int*)d_in[2];
    const int*   num_list = (const int*)d_in[3];
    const float* Wm       = (const float*)d_in[4];
    const float* gamma_   = (const float*)d_in[5];
    const float* beta_    = (const float*)d_in[6];

    const int B    = in_sizes[3];                 // 4
    const int Cout = in_sizes[5];                 // 128
    const int M    = in_sizes[1] / 3;             // 40000
    const int K3v  = in_sizes[2] / M;             // 27
    const int Cin  = (in_sizes[4] / Cout) / K3v;  // 64
    const int N    = in_sizes[0] / Cin;           // 200000
    const int Rtot = out_size / (Cout + 4);       // 8192
    const int K    = Rtot / B;                    // 2048

    float* out_feat = (float*)d_out;
    float* out_coor = out_feat + (size_t)Rtot * Cout;

    unsigned short* pk = (unsigned short*)d_ws;
    int* flags = (int*)((char*)d_ws + PK_BYTES);

    const int pack_grid = (NT * KCHP * 64) / 256;       // 112
    pack_w<<<dim3(pack_grid), dim3(256), 0, stream>>>(Wm, vidx, num_list, B, pk, flags);

    const int tiles = (Rtot + TM - 1) / TM;             // 512
    dpc_mfma<<<dim3(tiles), dim3(512), 0, stream>>>(
        features, center, vidx, num_list, pk, flags, gamma_, beta_,
        out_feat, out_coor, N, M, B, K, Rtot);
}